// Round 4
// baseline (183.710 us; speedup 1.0000x reference)
//
#include <hip/hip_runtime.h>
#include <cstdint>
#include <cstddef>

#define A_TOTAL 82944   // 96*96*9
#define NUM_C   80
#define NBOX    32
#define EMB_C   128
#define IDS     500
#define HW      9216    // 96*96
#define FM_W    96
#define BATCH   4
#define ABLK    256                 // anchors per block
#define NBLK    (A_TOTAL / ABLK)    // 324 assign blocks per image
#define REID_OFF 8192               // float offset of reid partials in ws

typedef float floatx4 __attribute__((ext_vector_type(4)));  // nontemporal-compatible

__device__ __forceinline__ float wave_sum(float v) {
#pragma unroll
    for (int o = 32; o > 0; o >>= 1) v += __shfl_down(v, o, 64);
    return v;
}
__device__ __forceinline__ float wave_max(float v) {
#pragma unroll
    for (int o = 32; o > 0; o >>= 1) v = fmaxf(v, __shfl_down(v, o, 64));
    return v;
}

// -------- Kernel 1 (fused): ReID for bx<NBOX (launched FIRST so the
// latency-bound blocks overlap the BW-bound assign blocks instead of
// trailing them), IoU+focal+reg for bx>=NBOX.
// grid: (NBOX+NBLK, B), block: 256. Per-block partials -> ws (no atomics).
// assign: ws[(b*NBLK + blk)*4 + {0,1,2}] = {num_pos, cls_sum, reg_sum}
// reid:   ws[REID_OFF + (b*NBOX+n)*2 + {0,1}] = {ce*valid, valid}
__global__ __launch_bounds__(256) void main_kernel(
    const float* __restrict__ cls, const float* __restrict__ reg,
    const float* __restrict__ anchors, const float* __restrict__ boxes,
    const int* __restrict__ labels, const float* __restrict__ emb,
    const int* __restrict__ reids, const float* __restrict__ Wt,
    const float* __restrict__ bt, const float* __restrict__ emb_scale,
    float* __restrict__ ws)
{
    const int b   = blockIdx.y;
    const int tid = threadIdx.x;

    // ---- shared state (both paths; block-uniform branch) ----
    __shared__ float4 sbox[NBOX];
    __shared__ int    slab[NBOX];
    __shared__ float  sarea[NBOX];
    __shared__ float4 subb;            // union bbox of all 32 boxes (x1,y1,x2,y2)
    __shared__ int    slabenc[ABLK];   // label if pos, -2 if neg, -1 if ignore
    __shared__ float  sred3[3][4];
    __shared__ float  sfeat[EMB_C];
    __shared__ float  slog[IDS];
    __shared__ float  sredR[4];
    __shared__ float  sb[2];           // [0]=scale [1]=max

    if (blockIdx.x < NBOX) {
        // ================= ReID path (one box per block, 256 threads) ======
        const int n = blockIdx.x;
        const float4 bx = ((const float4*)boxes)[b * NBOX + n];
        const int cx = (int)floorf((bx.x + bx.z) * 0.125f);
        const int cy = (int)floorf((bx.y + bx.w) * 0.125f);
        const int ind = cy * FM_W + cx;

        float sq = 0.f;
        if (tid < EMB_C) {
            const float v = emb[((size_t)b * EMB_C + tid) * HW + ind];
            sfeat[tid] = v;
            sq = v * v;
        }
        const float wsq = wave_sum(sq);
        if ((tid & 63) == 0) sredR[tid >> 6] = wsq;
        __syncthreads();
        if (tid == 0) {
            const float nrm = sqrtf(sredR[0] + sredR[1]);
            sb[0] = emb_scale[0] / fmaxf(nrm, 1e-12f);
        }
        __syncthreads();
        if (tid < EMB_C) sfeat[tid] *= sb[0];
        __syncthreads();

        // logits: thread owns columns tid and tid+256 (coalesced in Wt rows)
        const int  j1   = tid + 256;
        const bool has1 = (j1 < IDS);
        const float* w0col = Wt + tid;
        const float* w1col = Wt + (has1 ? j1 : tid);
        float al0 = bt[tid];
        float al1 = has1 ? bt[j1] : 0.f;
#pragma unroll 8
        for (int c = 0; c < EMB_C; ++c) {
            const float fv = sfeat[c];
            al0 = fmaf(fv, w0col[c * IDS], al0);
            al1 = fmaf(fv, w1col[c * IDS], al1);
        }
        slog[tid] = al0;
        if (has1) slog[j1] = al1;

        float m = has1 ? fmaxf(al0, al1) : al0;
        m = wave_max(m);
        if ((tid & 63) == 0) sredR[tid >> 6] = m;
        __syncthreads();                     // also publishes slog
        if (tid == 0) {
            float mm = sredR[0];
#pragma unroll
            for (int i = 1; i < 4; ++i) mm = fmaxf(mm, sredR[i]);
            sb[1] = mm;
        }
        __syncthreads();
        m = sb[1];

        float se = expf(al0 - m) + (has1 ? expf(al1 - m) : 0.f);
        se = wave_sum(se);
        if ((tid & 63) == 0) sredR[tid >> 6] = se;
        __syncthreads();
        if (tid == 0) {
            const float sum = sredR[0] + sredR[1] + sredR[2] + sredR[3];
            const int rid = reids[b * NBOX + n];
            const float valid = (rid >= 0) ? 1.f : 0.f;
            const int t = rid < 0 ? 0 : rid;
            const float ce = -(slog[t] - m - logf(sum));
            float* o = ws + REID_OFF + ((size_t)b * NBOX + n) * 2;
            o[0] = ce * valid;
            o[1] = valid;
        }
        return;
    }

    // ================= assign + focal + reg path ===========================
    const int blk = blockIdx.x - NBOX;
    const int a0  = blk * ABLK;

    // Prefetch focal group 0 (5x float4, addresses independent of everything)
    // so the cold HBM latency overlaps the IoU/assignment phase.
    const floatx4* crow =
        (const floatx4*)(cls + ((size_t)b * A_TOTAL + a0) * NUM_C);
    floatx4 buf0[5];
#pragma unroll
    for (int i = 0; i < 5; ++i)
        buf0[i] = __builtin_nontemporal_load(&crow[tid + i * 256]);

    float ux1 = 1e30f, uy1 = 1e30f, ux2 = -1e30f, uy2 = -1e30f;
    if (tid < NBOX) {
        const float4 bx = ((const float4*)boxes)[b * NBOX + tid];
        sbox[tid]  = bx;
        slab[tid]  = labels[b * NBOX + tid];
        sarea[tid] = (bx.z - bx.x) * (bx.w - bx.y);
        ux1 = bx.x; uy1 = bx.y; ux2 = bx.z; uy2 = bx.w;
    }
    if (tid < 64) {                      // whole wave 0 active for shuffles
#pragma unroll
        for (int o = 32; o > 0; o >>= 1) {
            ux1 = fminf(ux1, __shfl_down(ux1, o, 64));
            uy1 = fminf(uy1, __shfl_down(uy1, o, 64));
            ux2 = fmaxf(ux2, __shfl_down(ux2, o, 64));
            uy2 = fmaxf(uy2, __shfl_down(uy2, o, 64));
        }
        if (tid == 0) subb = make_float4(ux1, uy1, ux2, uy2);
    }
    __syncthreads();

    // ---- per-thread anchor assignment ----
    const int a = a0 + tid;
    const float4 an = ((const float4*)anchors)[a];       // (y1,x1,y2,x2)
    const float area_a = (an.z - an.x) * (an.w - an.y);
    float best = -1.f; int arg = 0;
    const float4 ub = subb;
    // early-out: no overlap with union bbox of all boxes => every IoU is 0
    if (fminf(an.w, ub.z) > fmaxf(an.y, ub.x) &&
        fminf(an.z, ub.w) > fmaxf(an.x, ub.y)) {
#pragma unroll
        for (int n = 0; n < NBOX; ++n) {
            const float4 bx = sbox[n];                   // (x1,y1,x2,y2)
            float iw = fmaxf(fminf(an.w, bx.z) - fmaxf(an.y, bx.x), 0.f);
            float ih = fmaxf(fminf(an.z, bx.w) - fmaxf(an.x, bx.y), 0.f);
            float inter = iw * ih;
            float ua  = fmaxf(area_a + sarea[n] - inter, 1e-8f);
            float iou = inter / ua;                      // full-precision (bit-exact decisions)
            if (iou > best) { best = iou; arg = n; }     // strict > : first max
        }
    }
    const bool pos = best >= 0.5f;
    const bool neg = best < 0.4f;
    slabenc[tid] = pos ? slab[arg] : (neg ? -2 : -1);

    float reg_part = 0.f, np_part = 0.f;
    if (pos) {
        np_part = 1.f;
        const float4 ab = sbox[arg];
        float gw  = ab.z - ab.x, gh = ab.w - ab.y;
        float gcx = ab.x + 0.5f * gw, gcy = ab.y + 0.5f * gh;
        gw = fmaxf(gw, 1.f); gh = fmaxf(gh, 1.f);
        const float aw  = an.w - an.y, ah = an.z - an.x;
        const float acx = an.y + 0.5f * aw, acy = an.x + 0.5f * ah;
        const float t0 = (gcy - acy) / ah;
        const float t1 = (gcx - acx) / aw;
        const float t2 = logf(gh / ah);
        const float t3 = logf(gw / aw);
        const float4 rg = ((const float4*)reg)[(size_t)b * A_TOTAL + a];
        float dd[4] = { fabsf(t0 - rg.x), fabsf(t1 - rg.y),
                        fabsf(t2 - rg.z), fabsf(t3 - rg.w) };
#pragma unroll
        for (int k = 0; k < 4; ++k) {
            const float d = dd[k];
            reg_part += (d <= (1.f/9.f)) ? (4.5f * d * d) : (d - (0.5f/9.f));
        }
    }
    __syncthreads();

    // ---- focal loss: uniform negative term + rare positive correction.
    // neg elem: 0.75*p^2*(-log(1-p))  -> accumulate p^2*log(1-p), scale -0.75*gate
    // pos elem (<= 1 per row): add 0.25*(1-p)^2*(-log p), remove its neg term.
    const float LO = 1e-4f;
    const float HI = (float)(1.0 - 1e-4);
    float cls_part = 0.f;
#pragma unroll
    for (int g = 0; g < 4; ++g) {
        floatx4 buf[5];
#pragma unroll
        for (int i = 0; i < 5; ++i) {
            if (g == 0) {
                buf[i] = buf0[i];     // prefetched before the IoU phase
            } else {
                const int f = tid + (g * 5 + i) * 256;
                buf[i] = __builtin_nontemporal_load(&crow[f]);
            }
        }
#pragma unroll
        for (int i = 0; i < 5; ++i) {
            const int f    = tid + (g * 5 + i) * 256;
            const int row  = f / 20;          // anchor within block
            const int col4 = f - row * 20;    // float4 within row
            const int enc  = slabenc[row];
            const int rel  = enc - col4 * 4;  // one-hot lane in [0,4) iff pos row
            const float gm = (enc != -1) ? -0.75f : 0.f;
            const float pv[4] = { buf[i].x, buf[i].y, buf[i].z, buf[i].w };
            float acc4 = 0.f;
#pragma unroll
            for (int j = 0; j < 4; ++j) {
                const float p = fminf(fmaxf(pv[j], LO), HI);
                acc4 = fmaf(p * p, __logf(1.f - p), acc4);
            }
            cls_part = fmaf(acc4, gm, cls_part);
            if ((unsigned)rel < 4u) {         // rare: pos row & one-hot in this float4
                float p = (rel == 0) ? pv[0] : (rel == 1) ? pv[1]
                        : (rel == 2) ? pv[2] : pv[3];
                p = fminf(fmaxf(p, LO), HI);
                const float negT = 0.75f * p * p * (-__logf(1.f - p));
                const float posT = 0.25f * (1.f - p) * (1.f - p) * (-__logf(p));
                cls_part += posT - negT;      // gate==1 for pos rows
            }
        }
    }

    // ---- block reduction, plain store (no atomics) ----
    const float w0 = wave_sum(cls_part);
    const float w1 = wave_sum(reg_part);
    const float w2 = wave_sum(np_part);
    const int wid = tid >> 6, lane = tid & 63;
    if (lane == 0) { sred3[0][wid] = w0; sred3[1][wid] = w1; sred3[2][wid] = w2; }
    __syncthreads();
    if (tid == 0) {
        float* o = ws + ((size_t)b * NBLK + blk) * 4;
        o[0] = sred3[2][0] + sred3[2][1] + sred3[2][2] + sred3[2][3];  // num_pos
        o[1] = sred3[0][0] + sred3[0][1] + sred3[0][2] + sred3[0][3];  // cls
        o[2] = sred3[1][0] + sred3[1][1] + sred3[1][2] + sred3[1][3];  // reg
    }
}

// -------- Kernel 2: finalize (1 block, wave w = image b) -------------------
__global__ __launch_bounds__(256) void finalize_kernel(
    const float* __restrict__ ws, float* __restrict__ out)
{
    __shared__ float s[BATCH][3];
    const int tid  = threadIdx.x;
    const int b    = tid >> 6;
    const int lane = tid & 63;

    float np = 0.f, cl = 0.f, rg = 0.f, ce = 0.f, va = 0.f;
    for (int i = lane; i < NBLK; i += 64) {
        const float* p = ws + ((size_t)b * NBLK + i) * 4;
        np += p[0]; cl += p[1]; rg += p[2];
    }
    if (lane < NBOX) {
        const float* r = ws + REID_OFF + ((size_t)b * NBOX + lane) * 2;
        ce = r[0]; va = r[1];
    }
    np = wave_sum(np); cl = wave_sum(cl); rg = wave_sum(rg);
    ce = wave_sum(ce); va = wave_sum(va);
    if (lane == 0) {
        const float cls_l = cl / fmaxf(np, 1.f);
        const float reg_l = rg / fmaxf(np * 4.f, 1.f);
        const float id_l  = ce / fmaxf(va, 1.f);
        s[b][0] = cls_l;
        s[b][1] = reg_l;
        s[b][2] = (np > 0.f) ? id_l : 0.f;
    }
    __syncthreads();
    if (tid == 0) {
        out[0] = (s[0][0] + s[1][0] + s[2][0] + s[3][0]) * 0.25f;
        out[1] = (s[0][1] + s[1][1] + s[2][1] + s[3][1]) * 0.25f * 50.f;
        out[2] = (s[0][2] + s[1][2] + s[2][2] + s[3][2]) * 0.25f;
    }
}

extern "C" void kernel_launch(void* const* d_in, const int* in_sizes, int n_in,
                              void* d_out, int out_size, void* d_ws, size_t ws_size,
                              hipStream_t stream) {
    const float* cls      = (const float*)d_in[0];
    const float* reg      = (const float*)d_in[1];
    const float* anchors  = (const float*)d_in[2];
    const float* emb      = (const float*)d_in[3];
    const float* boxes    = (const float*)d_in[4];
    const int*   labels   = (const int*)d_in[5];
    const int*   reids    = (const int*)d_in[6];
    const float* Wt       = (const float*)d_in[7];
    const float* bt       = (const float*)d_in[8];
    const float* escale   = (const float*)d_in[9];
    float* out = (float*)d_out;
    float* ws  = (float*)d_ws;

    dim3 g1(NBOX + NBLK, BATCH);
    main_kernel<<<g1, dim3(256), 0, stream>>>(cls, reg, anchors, boxes, labels,
                                              emb, reids, Wt, bt, escale, ws);
    finalize_kernel<<<1, 256, 0, stream>>>(ws, out);
}

// Round 5
// 180.904 us; speedup vs baseline: 1.0155x; 1.0155x over previous
//
#include <hip/hip_runtime.h>
#include <cstdint>
#include <cstddef>

#define A_TOTAL 82944   // 96*96*9
#define NUM_C   80
#define NBOX    32
#define EMB_C   128
#define IDS     500
#define HW      9216    // 96*96
#define FM_W    96
#define BATCH   4
#define ABLK    256                 // anchors per block
#define NBLK    (A_TOTAL / ABLK)    // 324 assign blocks per image
#define REID_OFF 8192               // float offset of reid partials in ws

typedef float floatx4 __attribute__((ext_vector_type(4)));  // nontemporal-compatible

__device__ __forceinline__ float wave_sum(float v) {
#pragma unroll
    for (int o = 32; o > 0; o >>= 1) v += __shfl_down(v, o, 64);
    return v;
}
__device__ __forceinline__ float wave_max(float v) {
#pragma unroll
    for (int o = 32; o > 0; o >>= 1) v = fmaxf(v, __shfl_down(v, o, 64));
    return v;
}

// -------- Kernel 1 (fused): ReID for bx<NBOX (dispatched first so the
// latency-bound blocks overlap the BW-bound assign blocks), IoU+focal+reg
// for bx>=NBOX. grid: (NBOX+NBLK, B), block: 256. Partials -> ws, no atomics.
// assign: ws[(b*NBLK + blk)*4 + {0,1,2}] = {num_pos, cls_sum, reg_sum}
// reid:   ws[REID_OFF + (b*NBOX+n)*2 + {0,1}] = {ce*valid, valid}
__global__ __launch_bounds__(256) void main_kernel(
    const float* __restrict__ cls, const float* __restrict__ reg,
    const float* __restrict__ anchors, const float* __restrict__ boxes,
    const int* __restrict__ labels, const float* __restrict__ emb,
    const int* __restrict__ reids, const float* __restrict__ Wt,
    const float* __restrict__ bt, const float* __restrict__ emb_scale,
    float* __restrict__ ws)
{
    const int b   = blockIdx.y;
    const int tid = threadIdx.x;

    __shared__ float4 sbox[NBOX];
    __shared__ int    slab[NBOX];
    __shared__ float  sarea[NBOX];
    __shared__ float4 subb;            // union bbox of all 32 boxes (x1,y1,x2,y2)
    __shared__ int    slabenc[ABLK];   // label if pos, -2 if neg, -1 if ignore
    __shared__ float  sred3[3][4];
    __shared__ float  sfeat[EMB_C];
    __shared__ float  slog[IDS];
    __shared__ float  sredR[4];
    __shared__ float  sb[2];           // [0]=scale [1]=max

    if (blockIdx.x < NBOX) {
        // ================= ReID path (one box per block, 256 threads) ======
        const int n = blockIdx.x;
        const float4 bx = ((const float4*)boxes)[b * NBOX + n];
        const int cx = (int)floorf((bx.x + bx.z) * 0.125f);
        const int cy = (int)floorf((bx.y + bx.w) * 0.125f);
        const int ind = cy * FM_W + cx;

        float sq = 0.f;
        if (tid < EMB_C) {
            const float v = emb[((size_t)b * EMB_C + tid) * HW + ind];
            sfeat[tid] = v;
            sq = v * v;
        }
        const float wsq = wave_sum(sq);
        if ((tid & 63) == 0) sredR[tid >> 6] = wsq;
        __syncthreads();
        if (tid == 0) {
            const float nrm = sqrtf(sredR[0] + sredR[1]);
            sb[0] = emb_scale[0] / fmaxf(nrm, 1e-12f);
        }
        __syncthreads();
        if (tid < EMB_C) sfeat[tid] *= sb[0];
        __syncthreads();

        // logits: thread owns columns tid and tid+256 (coalesced in Wt rows)
        const int  j1   = tid + 256;
        const bool has1 = (j1 < IDS);
        const float* w0col = Wt + tid;
        const float* w1col = Wt + (has1 ? j1 : tid);
        float al0 = bt[tid];
        float al1 = has1 ? bt[j1] : 0.f;
#pragma unroll 8
        for (int c = 0; c < EMB_C; ++c) {
            const float fv = sfeat[c];
            al0 = fmaf(fv, w0col[c * IDS], al0);
            al1 = fmaf(fv, w1col[c * IDS], al1);
        }
        slog[tid] = al0;
        if (has1) slog[j1] = al1;

        float m = has1 ? fmaxf(al0, al1) : al0;
        m = wave_max(m);
        if ((tid & 63) == 0) sredR[tid >> 6] = m;
        __syncthreads();                     // also publishes slog
        if (tid == 0) {
            float mm = sredR[0];
#pragma unroll
            for (int i = 1; i < 4; ++i) mm = fmaxf(mm, sredR[i]);
            sb[1] = mm;
        }
        __syncthreads();
        m = sb[1];

        float se = expf(al0 - m) + (has1 ? expf(al1 - m) : 0.f);
        se = wave_sum(se);
        if ((tid & 63) == 0) sredR[tid >> 6] = se;
        __syncthreads();
        if (tid == 0) {
            const float sum = sredR[0] + sredR[1] + sredR[2] + sredR[3];
            const int rid = reids[b * NBOX + n];
            const float valid = (rid >= 0) ? 1.f : 0.f;
            const int t = rid < 0 ? 0 : rid;
            const float ce = -(slog[t] - m - logf(sum));
            float* o = ws + REID_OFF + ((size_t)b * NBOX + n) * 2;
            o[0] = ce * valid;
            o[1] = valid;
        }
        return;
    }

    // ================= assign + focal + reg path ===========================
    const int blk = blockIdx.x - NBOX;
    const int a0  = blk * ABLK;
    const floatx4* crow =
        (const floatx4*)(cls + ((size_t)b * A_TOTAL + a0) * NUM_C);

    float ux1 = 1e30f, uy1 = 1e30f, ux2 = -1e30f, uy2 = -1e30f;
    if (tid < NBOX) {
        const float4 bx = ((const float4*)boxes)[b * NBOX + tid];
        sbox[tid]  = bx;
        slab[tid]  = labels[b * NBOX + tid];
        sarea[tid] = (bx.z - bx.x) * (bx.w - bx.y);
        ux1 = bx.x; uy1 = bx.y; ux2 = bx.z; uy2 = bx.w;
    }
    if (tid < 64) {                      // whole wave 0 active for shuffles
#pragma unroll
        for (int o = 32; o > 0; o >>= 1) {
            ux1 = fminf(ux1, __shfl_down(ux1, o, 64));
            uy1 = fminf(uy1, __shfl_down(uy1, o, 64));
            ux2 = fmaxf(ux2, __shfl_down(ux2, o, 64));
            uy2 = fmaxf(uy2, __shfl_down(uy2, o, 64));
        }
        if (tid == 0) subb = make_float4(ux1, uy1, ux2, uy2);
    }
    __syncthreads();

    // ---- per-thread anchor assignment ----
    const int a = a0 + tid;
    const float4 an = ((const float4*)anchors)[a];       // (y1,x1,y2,x2)
    const float area_a = (an.z - an.x) * (an.w - an.y);
    float best = -1.f; int arg = 0;
    const float4 ub = subb;
    // early-out: no overlap with union bbox of all boxes => every IoU is 0
    if (fminf(an.w, ub.z) > fmaxf(an.y, ub.x) &&
        fminf(an.z, ub.w) > fmaxf(an.x, ub.y)) {
#pragma unroll
        for (int n = 0; n < NBOX; ++n) {
            const float4 bx = sbox[n];                   // (x1,y1,x2,y2)
            float iw = fmaxf(fminf(an.w, bx.z) - fmaxf(an.y, bx.x), 0.f);
            float ih = fmaxf(fminf(an.z, bx.w) - fmaxf(an.x, bx.y), 0.f);
            float inter = iw * ih;
            float ua  = fmaxf(area_a + sarea[n] - inter, 1e-8f);
            float iou = inter / ua;                      // full-precision (bit-exact decisions)
            if (iou > best) { best = iou; arg = n; }     // strict > : first max
        }
    }
    const bool pos = best >= 0.5f;
    const bool neg = best < 0.4f;
    slabenc[tid] = pos ? slab[arg] : (neg ? -2 : -1);

    // Issue focal group-0 loads NOW: their ~900-cycle HBM latency hides under
    // the (rare-lane) pos processing and the barrier. Short live range.
    floatx4 bufA[5], bufB[5];
#pragma unroll
    for (int i = 0; i < 5; ++i)
        bufA[i] = __builtin_nontemporal_load(&crow[tid + i * 256]);

    float reg_part = 0.f, np_part = 0.f;
    if (pos) {
        np_part = 1.f;
        const float4 ab = sbox[arg];
        float gw  = ab.z - ab.x, gh = ab.w - ab.y;
        float gcx = ab.x + 0.5f * gw, gcy = ab.y + 0.5f * gh;
        gw = fmaxf(gw, 1.f); gh = fmaxf(gh, 1.f);
        const float aw  = an.w - an.y, ah = an.z - an.x;
        const float acx = an.y + 0.5f * aw, acy = an.x + 0.5f * ah;
        const float t0 = (gcy - acy) / ah;
        const float t1 = (gcx - acx) / aw;
        const float t2 = logf(gh / ah);
        const float t3 = logf(gw / aw);
        const float4 rg = ((const float4*)reg)[(size_t)b * A_TOTAL + a];
        float dd[4] = { fabsf(t0 - rg.x), fabsf(t1 - rg.y),
                        fabsf(t2 - rg.z), fabsf(t3 - rg.w) };
#pragma unroll
        for (int k = 0; k < 4; ++k) {
            const float d = dd[k];
            reg_part += (d <= (1.f/9.f)) ? (4.5f * d * d) : (d - (0.5f/9.f));
        }
    }
    __syncthreads();

    // ---- focal loss, 2-deep register-pipelined across the 4 groups:
    // group g+1's 5 nontemporal float4 loads are in flight while group g's
    // 20 elements are consumed (compiler emits counted vmcnt, so math
    // overlaps HBM latency instead of serializing load->wait->consume).
    // neg elem: 0.75*p^2*(-log(1-p)) -> accumulate p^2*log(1-p), scale -0.75
    // pos elem (<=1/row): add 0.25*(1-p)^2*(-log p), remove its neg term.
    const float LO = 1e-4f;
    const float HI = (float)(1.0 - 1e-4);
    float cls_part = 0.f;
#pragma unroll
    for (int g = 0; g < 4; ++g) {
        if (g < 3) {
#pragma unroll
            for (int i = 0; i < 5; ++i)
                bufB[i] = __builtin_nontemporal_load(&crow[tid + ((g + 1) * 5 + i) * 256]);
        }
#pragma unroll
        for (int i = 0; i < 5; ++i) {
            const int f    = tid + (g * 5 + i) * 256;
            const int row  = f / 20;          // anchor within block
            const int col4 = f - row * 20;    // float4 within row
            const int enc  = slabenc[row];
            const int rel  = enc - col4 * 4;  // one-hot lane in [0,4) iff pos row
            const float gm = (enc != -1) ? -0.75f : 0.f;
            const float pv[4] = { bufA[i].x, bufA[i].y, bufA[i].z, bufA[i].w };
            float acc4 = 0.f;
#pragma unroll
            for (int j = 0; j < 4; ++j) {
                const float p = fminf(fmaxf(pv[j], LO), HI);
                acc4 = fmaf(p * p, __logf(1.f - p), acc4);
            }
            cls_part = fmaf(acc4, gm, cls_part);
            if ((unsigned)rel < 4u) {         // rare: pos row & one-hot in this float4
                float p = (rel == 0) ? pv[0] : (rel == 1) ? pv[1]
                        : (rel == 2) ? pv[2] : pv[3];
                p = fminf(fmaxf(p, LO), HI);
                const float negT = 0.75f * p * p * (-__logf(1.f - p));
                const float posT = 0.25f * (1.f - p) * (1.f - p) * (-__logf(p));
                cls_part += posT - negT;      // gate==1 for pos rows
            }
        }
        if (g < 3) {
#pragma unroll
            for (int i = 0; i < 5; ++i) bufA[i] = bufB[i];   // register rotate (free)
        }
    }

    // ---- block reduction, plain store (no atomics) ----
    const float w0 = wave_sum(cls_part);
    const float w1 = wave_sum(reg_part);
    const float w2 = wave_sum(np_part);
    const int wid = tid >> 6, lane = tid & 63;
    if (lane == 0) { sred3[0][wid] = w0; sred3[1][wid] = w1; sred3[2][wid] = w2; }
    __syncthreads();
    if (tid == 0) {
        float* o = ws + ((size_t)b * NBLK + blk) * 4;
        o[0] = sred3[2][0] + sred3[2][1] + sred3[2][2] + sred3[2][3];  // num_pos
        o[1] = sred3[0][0] + sred3[0][1] + sred3[0][2] + sred3[0][3];  // cls
        o[2] = sred3[1][0] + sred3[1][1] + sred3[1][2] + sred3[1][3];  // reg
    }
}

// -------- Kernel 2: finalize (1 block, wave w = image b) -------------------
__global__ __launch_bounds__(256) void finalize_kernel(
    const float* __restrict__ ws, float* __restrict__ out)
{
    __shared__ float s[BATCH][3];
    const int tid  = threadIdx.x;
    const int b    = tid >> 6;
    const int lane = tid & 63;

    float np = 0.f, cl = 0.f, rg = 0.f, ce = 0.f, va = 0.f;
    for (int i = lane; i < NBLK; i += 64) {
        const float* p = ws + ((size_t)b * NBLK + i) * 4;
        np += p[0]; cl += p[1]; rg += p[2];
    }
    if (lane < NBOX) {
        const float* r = ws + REID_OFF + ((size_t)b * NBOX + lane) * 2;
        ce = r[0]; va = r[1];
    }
    np = wave_sum(np); cl = wave_sum(cl); rg = wave_sum(rg);
    ce = wave_sum(ce); va = wave_sum(va);
    if (lane == 0) {
        const float cls_l = cl / fmaxf(np, 1.f);
        const float reg_l = rg / fmaxf(np * 4.f, 1.f);
        const float id_l  = ce / fmaxf(va, 1.f);
        s[b][0] = cls_l;
        s[b][1] = reg_l;
        s[b][2] = (np > 0.f) ? id_l : 0.f;
    }
    __syncthreads();
    if (tid == 0) {
        out[0] = (s[0][0] + s[1][0] + s[2][0] + s[3][0]) * 0.25f;
        out[1] = (s[0][1] + s[1][1] + s[2][1] + s[3][1]) * 0.25f * 50.f;
        out[2] = (s[0][2] + s[1][2] + s[2][2] + s[3][2]) * 0.25f;
    }
}

extern "C" void kernel_launch(void* const* d_in, const int* in_sizes, int n_in,
                              void* d_out, int out_size, void* d_ws, size_t ws_size,
                              hipStream_t stream) {
    const float* cls      = (const float*)d_in[0];
    const float* reg      = (const float*)d_in[1];
    const float* anchors  = (const float*)d_in[2];
    const float* emb      = (const float*)d_in[3];
    const float* boxes    = (const float*)d_in[4];
    const int*   labels   = (const int*)d_in[5];
    const int*   reids    = (const int*)d_in[6];
    const float* Wt       = (const float*)d_in[7];
    const float* bt       = (const float*)d_in[8];
    const float* escale   = (const float*)d_in[9];
    float* out = (float*)d_out;
    float* ws  = (float*)d_ws;

    dim3 g1(NBOX + NBLK, BATCH);
    main_kernel<<<g1, dim3(256), 0, stream>>>(cls, reg, anchors, boxes, labels,
                                              emb, reids, Wt, bt, escale, ws);
    finalize_kernel<<<1, 256, 0, stream>>>(ws, out);
}